// Round 1
// baseline (937.560 us; speedup 1.0000x reference)
//
#include <hip/hip_runtime.h>
#include <math.h>

// Softmax splatting (softsplat, soft mode), fp32. B=4, C=16, H=512, W=960.
//
// New path (needs ~173 MB workspace):
//   P1: prep_kernel — fused binning (32x8 target tiles) + channels-last
//       prepack: inT[p][c] = in*exp(metric) (64 B/pixel, contiguous) and
//       fmT[p] = (dx, dy, m, 0). Turns the splat kernel's 19 scattered
//       per-entry loads into 5 contiguous 16-B loads.
//   P2: splat_kernel — one block per 32x8 target tile; acc 32x8x17 in LDS
//       (17.4 KB -> not LDS-occupancy-capped); CAP=768=3*256 so each thread
//       owns 3 independent entry slots, all loads issued up front (MLP=3).
// Fallback path: the previous verified kernel pair (877 us) if ws too small.

#define BB 4
#define CC 16
#define HH 512
#define WW 960
#define HWPROD (HH * WW)
#define EPSF 1e-7f

// ---------------- old (fallback) path constants ----------------
#define TSX 32
#define TSY 16
#define TNX (WW / TSX)              // 30
#define TNY (HH / TSY)              // 32
#define TPB (TNX * TNY)             // 960 tiles per batch
#define NTILE (BB * TPB)            // 3840
#define CAP 1536

// ---------------- new path constants ----------------
#define TSX2 32
#define TSY2 8
#define TNX2 (WW / TSX2)            // 30
#define TNY2 (HH / TSY2)            // 64
#define TPB2 (TNX2 * TNY2)          // 1920 tiles per batch
#define NTILE2 (BB * TPB2)          // 7680
#define CAP2 768                    // mean ~290, 2.6x headroom; = 3*256

// workspace layout (new path)
#define WS_BINS_OFF   ((size_t)32768)
#define WS_FMT_OFF    (WS_BINS_OFF + (size_t)NTILE2 * CAP2 * 4)      // 23,625,728
#define WS_INT_OFF    (WS_FMT_OFF + (size_t)BB * HWPROD * 16)        // 55,083,008
#define WS_NEED       (WS_INT_OFF + (size_t)BB * HWPROD * 64)        // 180,912,128

// ================= new path =================

__launch_bounds__(256)
__global__ void prep_kernel(const float* __restrict__ in,
                            const float* __restrict__ flow,
                            const float* __restrict__ metric,
                            unsigned int* __restrict__ counts,
                            unsigned int* __restrict__ bins,
                            float4* __restrict__ inT,
                            float4* __restrict__ fmT)
{
    __shared__ unsigned int lcnt[TPB2];   // phase1: local count; phase2: global base

    int b  = blockIdx.z;
    int x  = blockIdx.x * 32 + (threadIdx.x & 31);
    int y  = blockIdx.y * 8  + (threadIdx.x >> 5);
    int p  = y * WW + x;
    size_t bp = (size_t)b * HWPROD + p;

    for (int i = threadIdx.x; i < TPB2; i += 256) lcnt[i] = 0;
    __syncthreads();

    float dx = flow[(size_t)(b * 2 + 0) * HWPROD + p];
    float dy = flow[(size_t)(b * 2 + 1) * HWPROD + p];
    float m  = expf(metric[bp]);

    fmT[bp] = make_float4(dx, dy, m, 0.0f);

    // channels-last transpose, pre-multiplied by m (coalesced read + write)
    const float* inb = in + (size_t)b * CC * HWPROD + p;
#pragma unroll
    for (int k = 0; k < 4; ++k) {
        float4 o;
        o.x = inb[(size_t)(4 * k + 0) * HWPROD] * m;
        o.y = inb[(size_t)(4 * k + 1) * HWPROD] * m;
        o.z = inb[(size_t)(4 * k + 2) * HWPROD] * m;
        o.w = inb[(size_t)(4 * k + 3) * HWPROD] * m;
        inT[bp * 4 + k] = o;
    }

    // binning: which 32x8 target tiles does this source's 2x2 footprint touch?
    int x0 = (int)floorf((float)x + dx);
    int y0 = (int)floorf((float)y + dy);

    int txA = x0 >> 5, txB = (x0 + 1) >> 5;
    int tyA = y0 >> 3, tyB = (y0 + 1) >> 3;

    int          tA[4];
    unsigned int rA[4];
    int cnt = 0;

    #define TRYINS2(tx_, ty_)                                                  \
        if ((tx_) >= 0 && (tx_) < TNX2 && (ty_) >= 0 && (ty_) < TNY2) {        \
            int t_ = (ty_) * TNX2 + (tx_);                                     \
            rA[cnt] = atomicAdd(&lcnt[t_], 1u);                                \
            tA[cnt] = t_;                                                      \
            ++cnt;                                                             \
        }

    TRYINS2(txA, tyA);
    if (txB != txA) TRYINS2(txB, tyA);
    if (tyB != tyA) {
        TRYINS2(txA, tyB);
        if (txB != txA) TRYINS2(txB, tyB);
    }
    #undef TRYINS2

    __syncthreads();

    for (int i = threadIdx.x; i < TPB2; i += 256) {
        unsigned int c = lcnt[i];
        if (c) lcnt[i] = atomicAdd(&counts[b * TPB2 + i], c);
    }
    __syncthreads();

    unsigned int e = ((unsigned int)y << 10) | (unsigned int)x;
#pragma unroll
    for (int k = 0; k < 4; ++k) {     // static indexing (no scratch spill)
        if (k < cnt) {
            unsigned int pos = lcnt[tA[k]] + rA[k];
            if (pos < CAP2)
                bins[((size_t)b * TPB2 + tA[k]) * CAP2 + pos] = e;
        }
    }
}

__launch_bounds__(256)
__global__ void splat_kernel(const float4* __restrict__ inT,
                             const float4* __restrict__ fmT,
                             const unsigned int* __restrict__ counts,
                             const unsigned int* __restrict__ bins,
                             float* __restrict__ out)
{
    __shared__ float acc[TSX2 * TSY2 * 17];   // 17408 B: [pixel][c0..c15, w]

    int tile = blockIdx.x;
    int b  = tile / TPB2;
    int t  = tile - b * TPB2;
    int ty = t / TNX2;
    int tx = t - ty * TNX2;
    int tid = threadIdx.x;

    for (int i = tid; i < TSX2 * TSY2 * 17; i += 256) acc[i] = 0.0f;
    __syncthreads();

    unsigned int n = counts[tile];
    if (n > CAP2) n = CAP2;
    const unsigned int* bb = bins + (size_t)tile * CAP2;
    size_t base = (size_t)b * HWPROD;

    // CAP2 = 3*256: three independent entry slots per thread, all loads
    // issued up front -> 3 concurrent miss chains per thread.
    bool a0 = (unsigned int)tid       < n;
    bool a1 = (unsigned int)(tid+256) < n;
    bool a2 = (unsigned int)(tid+512) < n;
    unsigned int e0 = a0 ? bb[tid]       : 0u;
    unsigned int e1 = a1 ? bb[tid + 256] : 0u;
    unsigned int e2 = a2 ? bb[tid + 512] : 0u;

    int x_0 = (int)(e0 & 1023u), y_0 = (int)(e0 >> 10);
    int x_1 = (int)(e1 & 1023u), y_1 = (int)(e1 >> 10);
    int x_2 = (int)(e2 & 1023u), y_2 = (int)(e2 >> 10);
    size_t p0 = base + (size_t)(y_0 * WW + x_0);
    size_t p1 = base + (size_t)(y_1 * WW + x_1);
    size_t p2 = base + (size_t)(y_2 * WW + x_2);

    float4 fm0, fm1, fm2;
    float4 v00, v01, v02, v03;
    float4 v10, v11, v12, v13;
    float4 v20, v21, v22, v23;
    if (a0) { fm0 = fmT[p0]; const float4* ip = inT + p0 * 4;
              v00 = ip[0]; v01 = ip[1]; v02 = ip[2]; v03 = ip[3]; }
    if (a1) { fm1 = fmT[p1]; const float4* ip = inT + p1 * 4;
              v10 = ip[0]; v11 = ip[1]; v12 = ip[2]; v13 = ip[3]; }
    if (a2) { fm2 = fmT[p2]; const float4* ip = inT + p2 * 4;
              v20 = ip[0]; v21 = ip[1]; v22 = ip[2]; v23 = ip[3]; }

    #define PROC(aK, xK, yK, fmK, vA, vB, vC, vD)                              \
        if (aK) {                                                              \
            float fx = (float)(xK) + fmK.x;                                    \
            float fy = (float)(yK) + fmK.y;                                    \
            float x0f = floorf(fx), y0f = floorf(fy);                          \
            int   x0  = (int)x0f,   y0  = (int)y0f;                            \
            float wx1 = fx - x0f,   wy1 = fy - y0f;                            \
            float wx0 = 1.0f - wx1, wy0 = 1.0f - wy1;                          \
            float v[17];                                                       \
            v[0]=vA.x;  v[1]=vA.y;  v[2]=vA.z;  v[3]=vA.w;                     \
            v[4]=vB.x;  v[5]=vB.y;  v[6]=vB.z;  v[7]=vB.w;                     \
            v[8]=vC.x;  v[9]=vC.y;  v[10]=vC.z; v[11]=vC.w;                    \
            v[12]=vD.x; v[13]=vD.y; v[14]=vD.z; v[15]=vD.w;                    \
            v[16]=fmK.z;                                                       \
            const int   xs[4] = { x0,      x0 + 1,  x0,      x0 + 1  };        \
            const int   ys[4] = { y0,      y0,      y0 + 1,  y0 + 1  };        \
            const float ws[4] = { wx0*wy0, wx1*wy0, wx0*wy1, wx1*wy1 };        \
            _Pragma("unroll")                                                  \
            for (int k = 0; k < 4; ++k) {                                      \
                if ((xs[k] >> 5) == tx && (ys[k] >> 3) == ty) {                \
                    float wgt = ws[k];                                         \
                    int q = ((ys[k] & 7) * 32 + (xs[k] & 31)) * 17;            \
                    _Pragma("unroll")                                          \
                    for (int c = 0; c < 17; ++c)                               \
                        atomicAdd(&acc[q + c], v[c] * wgt);                    \
                }                                                              \
            }                                                                  \
        }

    PROC(a0, x_0, y_0, fm0, v00, v01, v02, v03)
    PROC(a1, x_1, y_1, fm1, v10, v11, v12, v13)
    PROC(a2, x_2, y_2, fm2, v20, v21, v22, v23)
    #undef PROC

    __syncthreads();

    // Dense writeback + fused normalization: exactly one pixel per thread.
    {
        int ly = tid >> 5, lx = tid & 31;
        int gp = (ty * TSY2 + ly) * WW + tx * TSX2 + lx;
        float inv = 1.0f / (acc[tid * 17 + 16] + EPSF);
        float* op = out + (size_t)b * CC * HWPROD + gp;
#pragma unroll
        for (int c = 0; c < CC; ++c)
            op[(size_t)c * HWPROD] = acc[tid * 17 + c] * inv;
    }
}

// ================= fallback (previous verified) path =================

__launch_bounds__(256)
__global__ void bin_kernel(const float* __restrict__ flow,
                           unsigned int* __restrict__ counts,
                           unsigned int* __restrict__ bins)
{
    __shared__ unsigned int lcnt[TPB];

    int b  = blockIdx.z;
    int x  = blockIdx.x * 32 + (threadIdx.x & 31);
    int y  = blockIdx.y * 8  + (threadIdx.x >> 5);
    int p  = y * WW + x;

    for (int i = threadIdx.x; i < TPB; i += 256) lcnt[i] = 0;
    __syncthreads();

    float dx = flow[(size_t)(b * 2 + 0) * HWPROD + p];
    float dy = flow[(size_t)(b * 2 + 1) * HWPROD + p];
    int x0 = (int)floorf((float)x + dx);
    int y0 = (int)floorf((float)y + dy);

    int txA = x0 >> 5, txB = (x0 + 1) >> 5;
    int tyA = y0 >> 4, tyB = (y0 + 1) >> 4;

    int          tA[4];
    unsigned int rA[4];
    int cnt = 0;

    #define TRYINS(tx_, ty_)                                                   \
        if ((tx_) >= 0 && (tx_) < TNX && (ty_) >= 0 && (ty_) < TNY) {          \
            int t_ = (ty_) * TNX + (tx_);                                      \
            rA[cnt] = atomicAdd(&lcnt[t_], 1u);                                \
            tA[cnt] = t_;                                                      \
            ++cnt;                                                             \
        }

    TRYINS(txA, tyA);
    if (txB != txA) TRYINS(txB, tyA);
    if (tyB != tyA) {
        TRYINS(txA, tyB);
        if (txB != txA) TRYINS(txB, tyB);
    }
    #undef TRYINS

    __syncthreads();

    for (int i = threadIdx.x; i < TPB; i += 256) {
        unsigned int c = lcnt[i];
        if (c) lcnt[i] = atomicAdd(&counts[b * TPB + i], c);
    }
    __syncthreads();

    unsigned int e = ((unsigned int)y << 10) | (unsigned int)x;
    for (int k = 0; k < cnt; ++k) {
        int t_ = tA[k];
        unsigned int pos = lcnt[t_] + rA[k];
        if (pos < CAP)
            bins[((size_t)(b * TPB) + t_) * CAP + pos] = e;
    }
}

__launch_bounds__(256)
__global__ void tile_kernel(const float* __restrict__ in,
                            const float* __restrict__ flow,
                            const float* __restrict__ metric,
                            const unsigned int* __restrict__ counts,
                            const unsigned int* __restrict__ bins,
                            float* __restrict__ out)
{
    __shared__ float acc[TSX * TSY * 17];

    int tile = blockIdx.x;
    int b  = tile / TPB;
    int t  = tile - b * TPB;
    int ty = t / TNX;
    int tx = t - ty * TNX;
    int tid = threadIdx.x;

    for (int i = tid; i < TSX * TSY * 17; i += 256) acc[i] = 0.0f;
    __syncthreads();

    unsigned int n = counts[tile];
    if (n > CAP) n = CAP;

    for (unsigned int base = 0; base < n; base += 256) {
        unsigned int i = base + tid;
        if (i < n) {
            unsigned int e = bins[(size_t)tile * CAP + i];
            int x = (int)(e & 1023u);
            int y = (int)(e >> 10);
            int p = y * WW + x;

            float dx = flow[(size_t)(b * 2 + 0) * HWPROD + p];
            float dy = flow[(size_t)(b * 2 + 1) * HWPROD + p];
            float m  = expf(metric[(size_t)b * HWPROD + p]);

            float fx = (float)x + dx;
            float fy = (float)y + dy;
            float x0f = floorf(fx), y0f = floorf(fy);
            int   x0  = (int)x0f,   y0  = (int)y0f;
            float wx1 = fx - x0f,   wy1 = fy - y0f;
            float wx0 = 1.0f - wx1, wy0 = 1.0f - wy1;

            float v[CC];
            const float* inp = in + (size_t)b * CC * HWPROD + p;
#pragma unroll
            for (int c = 0; c < CC; ++c) v[c] = inp[(size_t)c * HWPROD] * m;

            const int   xs[4] = { x0,        x0 + 1,    x0,        x0 + 1    };
            const int   ys[4] = { y0,        y0,        y0 + 1,    y0 + 1    };
            const float ws[4] = { wx0 * wy0, wx1 * wy0, wx0 * wy1, wx1 * wy1 };

#pragma unroll
            for (int k = 0; k < 4; ++k) {
                int xi = xs[k], yi = ys[k];
                if ((xi >> 5) == tx && (yi >> 4) == ty) {
                    float wgt = ws[k];
                    int q = ((yi & 15) * TSX + (xi & 31)) * 17;
#pragma unroll
                    for (int c = 0; c < CC; ++c)
                        atomicAdd(&acc[q + c], v[c] * wgt);
                    atomicAdd(&acc[q + CC], m * wgt);
                }
            }
        }
    }
    __syncthreads();

    for (int q = tid; q < TSX * TSY; q += 256) {
        int ly = q >> 5, lx = q & 31;
        int gp = (ty * TSY + ly) * WW + tx * TSX + lx;
        float inv = 1.0f / (acc[q * 17 + CC] + EPSF);
        float* op = out + (size_t)b * CC * HWPROD + gp;
#pragma unroll
        for (int c = 0; c < CC; ++c)
            op[(size_t)c * HWPROD] = acc[q * 17 + c] * inv;
    }
}

// ================= launch =================

extern "C" void kernel_launch(void* const* d_in, const int* in_sizes, int n_in,
                              void* d_out, int out_size, void* d_ws, size_t ws_size,
                              hipStream_t stream) {
    const float* in     = (const float*)d_in[0];
    const float* flow   = (const float*)d_in[1];
    const float* metric = (const float*)d_in[2];
    float* out = (float*)d_out;

    if (ws_size >= WS_NEED) {
        unsigned int* counts = (unsigned int*)d_ws;
        unsigned int* bins   = (unsigned int*)((char*)d_ws + WS_BINS_OFF);
        float4*       fmT    = (float4*)((char*)d_ws + WS_FMT_OFF);
        float4*       inT    = (float4*)((char*)d_ws + WS_INT_OFF);

        hipMemsetAsync(counts, 0, NTILE2 * sizeof(unsigned int), stream);

        prep_kernel<<<dim3(TNX2, TNY2, BB), dim3(256), 0, stream>>>(
            in, flow, metric, counts, bins, inT, fmT);
        splat_kernel<<<dim3(NTILE2), dim3(256), 0, stream>>>(
            inT, fmT, counts, bins, out);
    } else {
        // fallback: previous verified path (~877 us)
        unsigned int* counts = (unsigned int*)d_ws;
        unsigned int* bins   = (unsigned int*)((char*)d_ws + 16384);

        hipMemsetAsync(counts, 0, NTILE * sizeof(unsigned int), stream);

        bin_kernel<<<dim3(WW / 32, HH / 8, BB), dim3(256), 0, stream>>>(flow, counts, bins);
        tile_kernel<<<dim3(NTILE), dim3(256), 0, stream>>>(in, flow, metric, counts, bins, out);
    }
}

// Round 2
// 670.292 us; speedup vs baseline: 1.3987x; 1.3987x over previous
//
#include <hip/hip_runtime.h>
#include <math.h>

// Softmax splatting (softsplat, soft mode), fp32. B=4, C=16, H=512, W=960.
//
// v3: gather-owner design — NO LDS atomics (theory: ds_add_f32 atomic storm
// was the invariant ~700us wall across rounds 0 and 1).
//   prep3 : binning per 32x8 target band (one wave per band) with
//           pre-digested 16B entries {pack(p,rx0,ry0), wx1, wy1, m};
//           also builds channels-last inT[p][c] = in*exp(metric).
//   splat3: one wave per band; scans entries via v_readlane broadcast
//           (SGPR, no LDS); each thread owns a 1x4 pixel column and
//           accumulates 4x17 f32 in REGISTERS; <=4 lanes gather the 64B
//           value row from one broadcast address. Dense coalesced
//           writeback fused with normalization. Zero atomics/LDS/barriers.
// Fallback: original verified 877us pair if workspace too small.

#define BB 4
#define CC 16
#define HH 512
#define WW 960
#define HWPROD (HH * WW)
#define EPSF 1e-7f

// ---------------- v3 constants ----------------
#define BSX 32                       // band width
#define BSY 8                        // band height (one wave: 32 cols x 2 half-rows of 4)
#define NBX (WW / BSX)               // 30
#define NBY (HH / BSY)               // 64
#define BPB (NBX * NBY)              // 1920 bands per batch
#define NBAND (BB * BPB)             // 7680
#define CAPB 384                     // mean ~297, 5-sigma headroom

// workspace layout (v3): counts | bins | inT  = 173.0 MB (proven available)
#define WS_BINS_OFF ((size_t)32768)
#define WS_INT_OFF  (WS_BINS_OFF + (size_t)NBAND * CAPB * 16)   // 47,218,688
#define WS_NEED     (WS_INT_OFF + (size_t)BB * HWPROD * 64)     // 173,047,808

// ---------------- fallback constants ----------------
#define TSX 32
#define TSY 16
#define TNX (WW / TSX)
#define TNY (HH / TSY)
#define TPB (TNX * TNY)
#define NTILE (BB * TPB)
#define CAP 1536

// ================= v3 path =================

__launch_bounds__(256)
__global__ void prep3(const float* __restrict__ in,
                      const float* __restrict__ flow,
                      const float* __restrict__ metric,
                      unsigned int* __restrict__ counts,
                      uint4* __restrict__ bins,
                      float4* __restrict__ inT)
{
    __shared__ unsigned int lcnt[BPB];   // phase1: local count; phase2: global base

    int b  = blockIdx.z;
    int x  = blockIdx.x * 32 + (threadIdx.x & 31);
    int y  = blockIdx.y * 8  + (threadIdx.x >> 5);
    int p  = y * WW + x;
    size_t bp = (size_t)b * HWPROD + p;

    for (int i = threadIdx.x; i < BPB; i += 256) lcnt[i] = 0;
    __syncthreads();

    float dx = flow[(size_t)(b * 2 + 0) * HWPROD + p];
    float dy = flow[(size_t)(b * 2 + 1) * HWPROD + p];
    float m  = expf(metric[bp]);

    // channels-last transpose, pre-multiplied by m (coalesced read + write)
    const float* inb = in + (size_t)b * CC * HWPROD + p;
#pragma unroll
    for (int k = 0; k < 4; ++k) {
        float4 o;
        o.x = inb[(size_t)(4 * k + 0) * HWPROD] * m;
        o.y = inb[(size_t)(4 * k + 1) * HWPROD] * m;
        o.z = inb[(size_t)(4 * k + 2) * HWPROD] * m;
        o.w = inb[(size_t)(4 * k + 3) * HWPROD] * m;
        inT[bp * 4 + k] = o;
    }

    float fx = (float)x + dx;
    float fy = (float)y + dy;
    float x0f = floorf(fx), y0f = floorf(fy);
    int   x0  = (int)x0f,   y0  = (int)y0f;
    float wx1 = fx - x0f,   wy1 = fy - y0f;

    int bxA = x0 >> 5, bxB = (x0 + 1) >> 5;
    int byA = y0 >> 3, byB = (y0 + 1) >> 3;

    int          tA[4];
    unsigned int rA[4];
    int cnt = 0;

    #define TRYB(bx_, by_)                                                     \
        if ((bx_) >= 0 && (bx_) < NBX && (by_) >= 0 && (by_) < NBY) {          \
            int t_ = (by_) * NBX + (bx_);                                      \
            rA[cnt] = atomicAdd(&lcnt[t_], 1u);                                \
            tA[cnt] = t_;                                                      \
            ++cnt;                                                             \
        }

    TRYB(bxA, byA);
    if (bxB != bxA) TRYB(bxB, byA);
    if (byB != byA) {
        TRYB(bxA, byB);
        if (bxB != bxA) TRYB(bxB, byB);
    }
    #undef TRYB

    __syncthreads();

    // Allocate one contiguous global run per nonempty band; store base in lcnt.
    for (int i = threadIdx.x; i < BPB; i += 256) {
        unsigned int c = lcnt[i];
        if (c) lcnt[i] = atomicAdd(&counts[b * BPB + i], c);
    }
    __syncthreads();

#pragma unroll
    for (int k = 0; k < 4; ++k) {     // static indexing (no scratch spill)
        if (k < cnt) {
            int t_ = tA[k];
            unsigned int pos = lcnt[t_] + rA[k];
            if (pos < CAPB) {
                int by_ = t_ / NBX;
                int bx_ = t_ - by_ * NBX;
                unsigned int rx0 = (unsigned int)(x0 - (bx_ << 5) + 1);  // [0,32]
                unsigned int ry0 = (unsigned int)(y0 - (by_ << 3) + 1);  // [0,8]
                uint4 e;
                e.x = (unsigned int)p | (rx0 << 19) | (ry0 << 25);
                e.y = __float_as_uint(wx1);
                e.z = __float_as_uint(wy1);
                e.w = __float_as_uint(m);
                bins[((size_t)b * BPB + t_) * CAPB + pos] = e;
            }
        }
    }
}

__launch_bounds__(256)
__global__ void splat3(const float4* __restrict__ inT,
                       const unsigned int* __restrict__ counts,
                       const uint4* __restrict__ bins,
                       float* __restrict__ out)
{
    int band = blockIdx.x * 4 + (threadIdx.x >> 6);   // one band per wave
    int lane = threadIdx.x & 63;
    int b  = band / BPB;
    int t  = band - b * BPB;
    int by = t / NBX;
    int bx = t - by * NBX;

    int lx = lane & 31;          // owned column within band
    int r0 = (lane >> 5) * 4;    // owned rows: r0 .. r0+3

    // register accumulators: 4 rows x (16 channels + weight)
    float4 aA[4], aB[4], aC[4], aD[4];
    float  aw[4];
#pragma unroll
    for (int i = 0; i < 4; ++i) {
        aA[i] = make_float4(0.f, 0.f, 0.f, 0.f);
        aB[i] = make_float4(0.f, 0.f, 0.f, 0.f);
        aC[i] = make_float4(0.f, 0.f, 0.f, 0.f);
        aD[i] = make_float4(0.f, 0.f, 0.f, 0.f);
        aw[i] = 0.f;
    }

    unsigned int n = counts[band];
    if (n > CAPB) n = CAPB;
    const uint4*  bb  = bins + (size_t)band * CAPB;
    const float4* inb = inT + (size_t)b * HWPROD * 4;

    for (unsigned int base = 0; base < n; base += 64) {
        int lim = (int)(n - base); if (lim > 64) lim = 64;
        uint4 e = bb[base + lane];            // coalesced; lane-private stage
        for (int j = 0; j < lim; ++j) {
            // SGPR broadcast of entry j — no LDS, no shuffle network
            unsigned int pk = (unsigned int)__builtin_amdgcn_readlane((int)e.x, j);
            float wx1 = __uint_as_float(__builtin_amdgcn_readlane((int)e.y, j));
            float wy1 = __uint_as_float(__builtin_amdgcn_readlane((int)e.z, j));
            float m   = __uint_as_float(__builtin_amdgcn_readlane((int)e.w, j));

            int p  = (int)(pk & 0x7FFFFu);
            int cx = (int)((pk >> 19) & 63u) - 1;   // x0 rel to band  [-1,31]
            int cy = (int)((pk >> 25) & 15u) - 1;   // y0 rel to band  [-1,7]

            float wx = (lx == cx) ? (1.0f - wx1)
                     : ((lx == cx + 1) ? wx1 : 0.0f);
            bool rowhit = (cy + 1 >= r0) && (cy <= r0 + 3);

            if (wx != 0.0f && rowhit) {           // <=4 lanes active, same p
                const float4* ip = inb + (size_t)p * 4;
                float4 A = ip[0], Bv = ip[1], Cv = ip[2], Dv = ip[3];
                int iA = cy & 3, iB = (cy + 1) & 3;   // uniform (SGPR)
#pragma unroll
                for (int i = 0; i < 4; ++i) {
                    if (i == iA || i == iB) {         // uniform guard: skips 2/4 groups
                        int row = r0 + i;
                        float wyv = (row == cy)     ? (1.0f - wy1)
                                  : ((row == cy + 1) ? wy1 : 0.0f);
                        float w = wx * wyv;
                        aA[i].x += w * A.x;  aA[i].y += w * A.y;
                        aA[i].z += w * A.z;  aA[i].w += w * A.w;
                        aB[i].x += w * Bv.x; aB[i].y += w * Bv.y;
                        aB[i].z += w * Bv.z; aB[i].w += w * Bv.w;
                        aC[i].x += w * Cv.x; aC[i].y += w * Cv.y;
                        aC[i].z += w * Cv.z; aC[i].w += w * Cv.w;
                        aD[i].x += w * Dv.x; aD[i].y += w * Dv.y;
                        aD[i].z += w * Dv.z; aD[i].w += w * Dv.w;
                        aw[i]   += w * m;
                    }
                }
            }
        }
    }

    // Dense coalesced writeback + fused normalization (no LDS round-trip).
    int xg = bx * 32 + lx;
    float* ob = out + (size_t)b * CC * HWPROD;
#pragma unroll
    for (int i = 0; i < 4; ++i) {
        int yg = by * 8 + r0 + i;
        float inv = 1.0f / (aw[i] + EPSF);
        float* op = ob + (size_t)yg * WW + xg;
        op[(size_t) 0 * HWPROD] = aA[i].x * inv;
        op[(size_t) 1 * HWPROD] = aA[i].y * inv;
        op[(size_t) 2 * HWPROD] = aA[i].z * inv;
        op[(size_t) 3 * HWPROD] = aA[i].w * inv;
        op[(size_t) 4 * HWPROD] = aB[i].x * inv;
        op[(size_t) 5 * HWPROD] = aB[i].y * inv;
        op[(size_t) 6 * HWPROD] = aB[i].z * inv;
        op[(size_t) 7 * HWPROD] = aB[i].w * inv;
        op[(size_t) 8 * HWPROD] = aC[i].x * inv;
        op[(size_t) 9 * HWPROD] = aC[i].y * inv;
        op[(size_t)10 * HWPROD] = aC[i].z * inv;
        op[(size_t)11 * HWPROD] = aC[i].w * inv;
        op[(size_t)12 * HWPROD] = aD[i].x * inv;
        op[(size_t)13 * HWPROD] = aD[i].y * inv;
        op[(size_t)14 * HWPROD] = aD[i].z * inv;
        op[(size_t)15 * HWPROD] = aD[i].w * inv;
    }
}

// ================= fallback (original verified 877us) path =================

__launch_bounds__(256)
__global__ void bin_kernel(const float* __restrict__ flow,
                           unsigned int* __restrict__ counts,
                           unsigned int* __restrict__ bins)
{
    __shared__ unsigned int lcnt[TPB];

    int b  = blockIdx.z;
    int x  = blockIdx.x * 32 + (threadIdx.x & 31);
    int y  = blockIdx.y * 8  + (threadIdx.x >> 5);
    int p  = y * WW + x;

    for (int i = threadIdx.x; i < TPB; i += 256) lcnt[i] = 0;
    __syncthreads();

    float dx = flow[(size_t)(b * 2 + 0) * HWPROD + p];
    float dy = flow[(size_t)(b * 2 + 1) * HWPROD + p];
    int x0 = (int)floorf((float)x + dx);
    int y0 = (int)floorf((float)y + dy);

    int txA = x0 >> 5, txB = (x0 + 1) >> 5;
    int tyA = y0 >> 4, tyB = (y0 + 1) >> 4;

    int          tA[4];
    unsigned int rA[4];
    int cnt = 0;

    #define TRYINS(tx_, ty_)                                                   \
        if ((tx_) >= 0 && (tx_) < TNX && (ty_) >= 0 && (ty_) < TNY) {          \
            int t_ = (ty_) * TNX + (tx_);                                      \
            rA[cnt] = atomicAdd(&lcnt[t_], 1u);                                \
            tA[cnt] = t_;                                                      \
            ++cnt;                                                             \
        }

    TRYINS(txA, tyA);
    if (txB != txA) TRYINS(txB, tyA);
    if (tyB != tyA) {
        TRYINS(txA, tyB);
        if (txB != txA) TRYINS(txB, tyB);
    }
    #undef TRYINS

    __syncthreads();

    for (int i = threadIdx.x; i < TPB; i += 256) {
        unsigned int c = lcnt[i];
        if (c) lcnt[i] = atomicAdd(&counts[b * TPB + i], c);
    }
    __syncthreads();

    unsigned int e = ((unsigned int)y << 10) | (unsigned int)x;
    for (int k = 0; k < cnt; ++k) {
        int t_ = tA[k];
        unsigned int pos = lcnt[t_] + rA[k];
        if (pos < CAP)
            bins[((size_t)(b * TPB) + t_) * CAP + pos] = e;
    }
}

__launch_bounds__(256)
__global__ void tile_kernel(const float* __restrict__ in,
                            const float* __restrict__ flow,
                            const float* __restrict__ metric,
                            const unsigned int* __restrict__ counts,
                            const unsigned int* __restrict__ bins,
                            float* __restrict__ out)
{
    __shared__ float acc[TSX * TSY * 17];

    int tile = blockIdx.x;
    int b  = tile / TPB;
    int t  = tile - b * TPB;
    int ty = t / TNX;
    int tx = t - ty * TNX;
    int tid = threadIdx.x;

    for (int i = tid; i < TSX * TSY * 17; i += 256) acc[i] = 0.0f;
    __syncthreads();

    unsigned int n = counts[tile];
    if (n > CAP) n = CAP;

    for (unsigned int base = 0; base < n; base += 256) {
        unsigned int i = base + tid;
        if (i < n) {
            unsigned int e = bins[(size_t)tile * CAP + i];
            int x = (int)(e & 1023u);
            int y = (int)(e >> 10);
            int p = y * WW + x;

            float dx = flow[(size_t)(b * 2 + 0) * HWPROD + p];
            float dy = flow[(size_t)(b * 2 + 1) * HWPROD + p];
            float m  = expf(metric[(size_t)b * HWPROD + p]);

            float fx = (float)x + dx;
            float fy = (float)y + dy;
            float x0f = floorf(fx), y0f = floorf(fy);
            int   x0  = (int)x0f,   y0  = (int)y0f;
            float wx1 = fx - x0f,   wy1 = fy - y0f;
            float wx0 = 1.0f - wx1, wy0 = 1.0f - wy1;

            float v[CC];
            const float* inp = in + (size_t)b * CC * HWPROD + p;
#pragma unroll
            for (int c = 0; c < CC; ++c) v[c] = inp[(size_t)c * HWPROD] * m;

            const int   xs[4] = { x0,        x0 + 1,    x0,        x0 + 1    };
            const int   ys[4] = { y0,        y0,        y0 + 1,    y0 + 1    };
            const float ws[4] = { wx0 * wy0, wx1 * wy0, wx0 * wy1, wx1 * wy1 };

#pragma unroll
            for (int k = 0; k < 4; ++k) {
                int xi = xs[k], yi = ys[k];
                if ((xi >> 5) == tx && (yi >> 4) == ty) {
                    float wgt = ws[k];
                    int q = ((yi & 15) * TSX + (xi & 31)) * 17;
#pragma unroll
                    for (int c = 0; c < CC; ++c)
                        atomicAdd(&acc[q + c], v[c] * wgt);
                    atomicAdd(&acc[q + CC], m * wgt);
                }
            }
        }
    }
    __syncthreads();

    for (int q = tid; q < TSX * TSY; q += 256) {
        int ly = q >> 5, lx = q & 31;
        int gp = (ty * TSY + ly) * WW + tx * TSX + lx;
        float inv = 1.0f / (acc[q * 17 + CC] + EPSF);
        float* op = out + (size_t)b * CC * HWPROD + gp;
#pragma unroll
        for (int c = 0; c < CC; ++c)
            op[(size_t)c * HWPROD] = acc[q * 17 + c] * inv;
    }
}

// ================= launch =================

extern "C" void kernel_launch(void* const* d_in, const int* in_sizes, int n_in,
                              void* d_out, int out_size, void* d_ws, size_t ws_size,
                              hipStream_t stream) {
    const float* in     = (const float*)d_in[0];
    const float* flow   = (const float*)d_in[1];
    const float* metric = (const float*)d_in[2];
    float* out = (float*)d_out;

    if (ws_size >= WS_NEED) {
        unsigned int* counts = (unsigned int*)d_ws;
        uint4*        bins   = (uint4*)((char*)d_ws + WS_BINS_OFF);
        float4*       inT    = (float4*)((char*)d_ws + WS_INT_OFF);

        hipMemsetAsync(counts, 0, NBAND * sizeof(unsigned int), stream);

        prep3<<<dim3(NBX, NBY, BB), dim3(256), 0, stream>>>(
            in, flow, metric, counts, bins, inT);
        splat3<<<dim3(NBAND / 4), dim3(256), 0, stream>>>(
            inT, counts, bins, out);
    } else {
        // fallback: original verified path (~877 us)
        unsigned int* counts = (unsigned int*)d_ws;
        unsigned int* bins   = (unsigned int*)((char*)d_ws + 16384);

        hipMemsetAsync(counts, 0, NTILE * sizeof(unsigned int), stream);

        bin_kernel<<<dim3(WW / 32, HH / 8, BB), dim3(256), 0, stream>>>(flow, counts, bins);
        tile_kernel<<<dim3(NTILE), dim3(256), 0, stream>>>(in, flow, metric, counts, bins, out);
    }
}